// Round 8
// baseline (174.501 us; speedup 1.0000x reference)
//
#include <hip/hip_runtime.h>
#include <math.h>

// Problem constants (fixed by the reference)
constexpr int NN  = 4096;   // instances
constexpr int PP  = 2048;   // phrases
constexpr int EE  = 65536;  // edges
constexpr int DD  = 1024;   // feature dim
constexpr int OUTF = 128;   // gate MLP out dim
constexpr int G4  = 512;    // 4 gates * 128

typedef __attribute__((ext_vector_type(8))) short short8v;
typedef __attribute__((ext_vector_type(4))) float f32x4;

__device__ __forceinline__ float sigmoid_relu(float z) {
    z = fmaxf(z, 0.0f);
    return 1.0f / (1.0f + __expf(-z));
}
__device__ __forceinline__ float b2f(ushort u) {
    return __uint_as_float(((unsigned int)u) << 16);
}
__device__ __forceinline__ ushort f2b(float f) {  // RNE
    unsigned int x = __float_as_uint(f);
    return (ushort)((x + 0x7fffu + ((x >> 16) & 1u)) >> 16);
}
__device__ __forceinline__ unsigned int pack2(float a, float b) {
    return (unsigned int)f2b(a) | ((unsigned int)f2b(b) << 16);
}
__device__ __forceinline__ float lo16(unsigned int u) { return __uint_as_float(u << 16); }
__device__ __forceinline__ float hi16(unsigned int u) { return __uint_as_float(u & 0xffff0000u); }

#define GLD16(gptr, lptr) \
    __builtin_amdgcn_global_load_lds((__attribute__((address_space(1))) const void*)(gptr), \
                                     (__attribute__((address_space(3))) void*)(lptr), 16, 0, 0)
// Counted-vmcnt pipeline primitives (T4): keep just-issued loads in flight.
#define ASM_VMCNT(n) asm volatile("s_waitcnt vmcnt(" #n ")" ::: "memory")
#define BARRIER() do { asm volatile("" ::: "memory"); \
                       __builtin_amdgcn_s_barrier();  \
                       asm volatile("" ::: "memory"); } while (0)

// ---------------------------------------------------------------------------
// Fused prep: counter zeroing, f32->bf16 features, gate-weight pack,
// refine-weight transpose.
constexpr int NCNT    = 2 * (NN + NN + PP);        // 20480 ints (cnt + cur)
constexpr int NB_ZERO = NCNT / 256;                // 80
constexpr int NB_F2B  = (NN + PP) * DD / 4 / 256;  // 6144
constexpr int NB_PACK = G4 * DD / 256;             // 2048
constexpr int NB_WT   = 4 * (DD / 64) * (DD / 64); // 1024

__global__ __launch_bounds__(256) void prep_kernel(
        int* __restrict__ cntBlock,
        const float* __restrict__ instF, const float* __restrict__ phraF,
        ushort* __restrict__ instB, ushort* __restrict__ phraB,
        const float* __restrict__ psW, const float* __restrict__ poW,
        const float* __restrict__ opW, const float* __restrict__ spW,
        const float* __restrict__ psB, const float* __restrict__ poB,
        const float* __restrict__ opB, const float* __restrict__ spB,
        ushort* __restrict__ WiT, ushort* __restrict__ WpT,
        float* __restrict__ biascat,
        const float* __restrict__ W0, const float* __restrict__ W1,
        const float* __restrict__ W2, const float* __restrict__ W3,
        ushort* __restrict__ T0, ushort* __restrict__ T1,
        ushort* __restrict__ T2, ushort* __restrict__ T3) {
    __shared__ float tile[64][65];
    int b = blockIdx.x, t = threadIdx.x;
    if (b < NB_ZERO) {
        cntBlock[b * 256 + t] = 0;
        return;
    }
    b -= NB_ZERO;
    if (b < NB_F2B) {
        int i = b * 256 + t;
        constexpr int na4 = NN * DD / 4;
        if (i < na4) {
            float4 v = ((const float4*)instF)[i];
            ushort4 u; u.x = f2b(v.x); u.y = f2b(v.y); u.z = f2b(v.z); u.w = f2b(v.w);
            ((ushort4*)instB)[i] = u;
        } else {
            int j = i - na4;
            float4 v = ((const float4*)phraF)[j];
            ushort4 u; u.x = f2b(v.x); u.y = f2b(v.y); u.z = f2b(v.z); u.w = f2b(v.w);
            ((ushort4*)phraB)[j] = u;
        }
        return;
    }
    b -= NB_F2B;
    if (b < NB_PACK) {
        int idx = b * 256 + t;
        int n = idx >> 10, k = idx & 1023;
        int g = n >> 7, j = n & 127;
        float wi, wp;
        if (g == 0)      { wi = psW[(size_t)(DD + k) * OUTF + j]; wp = psW[(size_t)k * OUTF + j]; }
        else if (g == 1) { wi = poW[(size_t)(DD + k) * OUTF + j]; wp = poW[(size_t)k * OUTF + j]; }
        else if (g == 2) { wi = opW[(size_t)k * OUTF + j];        wp = opW[(size_t)(DD + k) * OUTF + j]; }
        else             { wi = spW[(size_t)k * OUTF + j];        wp = spW[(size_t)(DD + k) * OUTF + j]; }
        WiT[idx] = f2b(wi);
        WpT[idx] = f2b(wp);
        if (idx < G4) {
            int gg = idx >> 7, jj = idx & 127;
            biascat[idx] = (gg == 0) ? psB[jj] : (gg == 1) ? poB[jj]
                         : (gg == 2) ? opB[jj] : spB[jj];
        }
        return;
    }
    b -= NB_PACK;
    int z = b >> 8, rest = b & 255;
    const float* W = (z == 0) ? W0 : (z == 1) ? W1 : (z == 2) ? W2 : W3;
    ushort*      T = (z == 0) ? T0 : (z == 1) ? T1 : (z == 2) ? T2 : T3;
    int k0 = (rest & 15) * 64, n0 = (rest >> 4) * 64;
    int tx = t & 63, ty = t >> 6;
    #pragma unroll
    for (int i = 0; i < 64; i += 4)
        tile[ty + i][tx] = W[(size_t)(k0 + ty + i) * DD + n0 + tx];
    __syncthreads();
    #pragma unroll
    for (int i = 0; i < 64; i += 4)
        T[(size_t)(n0 + ty + i) * DD + k0 + tx] = f2b(tile[tx][ty + i]);
}

// ---------------------------------------------------------------------------
// Pipelined MFMA GEMM building blocks. A-tile 128 rows; B-tile BROWS rows.
// BK=64, XOR-swizzled linear LDS (rule 21).
template<int BROWS>
__device__ __forceinline__ void stage_tiles(const ushort* __restrict__ A,
                                            const ushort* __restrict__ BT,
                                            int bm, int bn, int k0,
                                            ushort* Asl, ushort* Bsl, int t) {
    #pragma unroll
    for (int r = 0; r < 4; r++) {
        int ch = r * 256 + t;
        int row = ch >> 3;
        int sw = ((ch & 7) ^ (row & 7)) << 3;
        GLD16(A + (size_t)(bm + row) * DD + k0 + sw, &Asl[ch * 8]);
    }
    #pragma unroll
    for (int r = 0; r < BROWS / 32; r++) {
        int ch = r * 256 + t;
        int row = ch >> 3;
        int sw = ((ch & 7) ^ (row & 7)) << 3;
        GLD16(BT + (size_t)(bn + row) * DD + k0 + sw, &Bsl[ch * 8]);
    }
}

template<int NACC>
__device__ __forceinline__ void compute_tiles(const ushort* Asl, const ushort* Bsl,
                                              f32x4 (&acc)[4][NACC],
                                              int wr, int wc, int lr, int lk) {
    #pragma unroll
    for (int kk = 0; kk < 2; kk++) {
        int ch16 = kk * 4 + lk;
        short8v a[4], b[NACC];
        #pragma unroll
        for (int m = 0; m < 4; m++) {
            int ra = wr + m * 16 + lr;
            a[m] = *(const short8v*)&Asl[ra * 64 + ((ch16 ^ (ra & 7)) << 3)];
        }
        #pragma unroll
        for (int n = 0; n < NACC; n++) {
            int rb = wc + n * 16 + lr;
            b[n] = *(const short8v*)&Bsl[rb * 64 + ((ch16 ^ (rb & 7)) << 3)];
        }
        #pragma unroll
        for (int m = 0; m < 4; m++)
            #pragma unroll
            for (int n = 0; n < NACC; n++)
                acc[m][n] = __builtin_amdgcn_mfma_f32_16x16x32_bf16(a[m], b[n], acc[m][n], 0, 0, 0);
    }
}

// ---------------------------------------------------------------------------
// Gate tables, 128x64 tile, counted-vmcnt 2-buffer pipeline.
__global__ __launch_bounds__(256) void mfma_tables_kernel(
        const ushort* __restrict__ instB, const ushort* __restrict__ WiT,
        const ushort* __restrict__ phraB, const ushort* __restrict__ WpT,
        const float* __restrict__ biascat,
        ushort* __restrict__ TiB, ushort* __restrict__ TpB) {
    __shared__ ushort Asl[2][128 * 64];
    __shared__ ushort Bsl[2][64 * 64];
    int bx = blockIdx.x;
    const ushort *A, *BT; ushort* C; const float* bias;
    if (bx < NN / 128) { A = instB; BT = WiT; C = TiB; bias = nullptr; }
    else { bx -= NN / 128; A = phraB; BT = WpT; C = TpB; bias = biascat; }
    int bm = bx * 128, bn = blockIdx.y * 64;
    int t = threadIdx.x;
    const int lane = t & 63, w = t >> 6;
    const int wr = (w >> 1) * 64, wc = (w & 1) * 32;
    const int lr = lane & 15, lk = lane >> 4;
    f32x4 acc[4][2] = {};

    int cur = 0;
    stage_tiles<64>(A, BT, bm, bn, 0, Asl[0], Bsl[0], t);
    for (int k0 = 0; k0 < DD; k0 += 64) {
        int nxt = cur ^ 1;
        if (k0 + 64 < DD) {
            stage_tiles<64>(A, BT, bm, bn, k0 + 64, Asl[nxt], Bsl[nxt], t);
            ASM_VMCNT(6);
        } else {
            ASM_VMCNT(0);
        }
        BARRIER();
        compute_tiles<2>(Asl[cur], Bsl[cur], acc, wr, wc, lr, lk);
        BARRIER();
        cur = nxt;
    }
    #pragma unroll
    for (int m = 0; m < 4; m++) {
        int row = bm + wr + m * 16 + lk * 4;
        #pragma unroll
        for (int n = 0; n < 2; n++) {
            int col = bn + wc + n * 16 + lr;
            float bv = bias ? bias[col] : 0.f;
            #pragma unroll
            for (int r = 0; r < 4; r++)
                C[(size_t)(row + r) * G4 + col] = f2b(acc[m][n][r] + bv);
        }
    }
}

// ---------------------------------------------------------------------------
// Fused refine: out = msg + relu(msg@W1+b1) + relu(feat@W2+b2).
// 128x64 tile (768 blocks), continuous counted-vmcnt pipeline.
__global__ __launch_bounds__(256) void mfma_refine_kernel(
        const ushort* __restrict__ imsgB, const ushort* __restrict__ instB,
        const ushort* __restrict__ iw1T, const ushort* __restrict__ iw2T,
        const float* __restrict__ ib1, const float* __restrict__ ib2,
        float* __restrict__ iout,
        const ushort* __restrict__ pmsgB, const ushort* __restrict__ phraB,
        const ushort* __restrict__ pw1T, const ushort* __restrict__ pw2T,
        const float* __restrict__ pb1, const float* __restrict__ pb2,
        float* __restrict__ pout) {
    __shared__ ushort Asl[2][128 * 64];
    __shared__ ushort Bsl[2][64 * 64];
    int bx = blockIdx.x;
    const ushort *Am, *Af, *W1, *W2; const float *b1, *b2; float* out;
    if (bx < NN / 128) {
        Am = imsgB; Af = instB; W1 = iw1T; W2 = iw2T; b1 = ib1; b2 = ib2; out = iout;
    } else {
        bx -= NN / 128;
        Am = pmsgB; Af = phraB; W1 = pw1T; W2 = pw2T; b1 = pb1; b2 = pb2; out = pout;
    }
    int bm = bx * 128, bn = blockIdx.y * 64;
    int t = threadIdx.x;
    const int lane = t & 63, w = t >> 6;
    const int wr = (w >> 1) * 64, wc = (w & 1) * 32;
    const int lr = lane & 15, lk = lane >> 4;
    f32x4 acc1[4][2] = {};
    f32x4 acc2[4][2] = {};

    int cur = 0;
    stage_tiles<64>(Am, W1, bm, bn, 0, Asl[0], Bsl[0], t);
    auto run = [&](const ushort* A, const ushort* B, f32x4 (&acc)[4][2],
                   const ushort* An, const ushort* Bn) {
        for (int k0 = 0; k0 < DD; k0 += 64) {
            int nxt = cur ^ 1;
            if (k0 + 64 < DD) {
                stage_tiles<64>(A, B, bm, bn, k0 + 64, Asl[nxt], Bsl[nxt], t);
                ASM_VMCNT(6);
            } else if (An) {
                stage_tiles<64>(An, Bn, bm, bn, 0, Asl[nxt], Bsl[nxt], t);
                ASM_VMCNT(6);
            } else {
                ASM_VMCNT(0);
            }
            BARRIER();
            compute_tiles<2>(Asl[cur], Bsl[cur], acc, wr, wc, lr, lk);
            BARRIER();
            cur = nxt;
        }
    };
    run(Am, W1, acc1, Af, W2);
    run(Af, W2, acc2, nullptr, nullptr);

    #pragma unroll
    for (int m = 0; m < 4; m++) {
        int row = bm + wr + m * 16 + lk * 4;
        #pragma unroll
        for (int n = 0; n < 2; n++) {
            int col = bn + wc + n * 16 + lr;
            float vb1 = b1[col], vb2 = b2[col];
            #pragma unroll
            for (int r = 0; r < 4; r++) {
                float v = b2f(Am[(size_t)(row + r) * DD + col])
                        + fmaxf(acc1[m][n][r] + vb1, 0.f)
                        + fmaxf(acc2[m][n][r] + vb2, 0.f);
                out[(size_t)(row + r) * DD + col] = v;
            }
        }
    }
}

// ---------------------------------------------------------------------------
// Counting sort: histogram + scan (scatter is folded into gate_kernel).
__global__ void hist_kernel(const int* __restrict__ s_idx, const int* __restrict__ o_idx,
                            const int* __restrict__ c_idx,
                            int* cntS, int* cntO, int* cntC) {
    int e = blockIdx.x * blockDim.x + threadIdx.x;
    if (e >= EE) return;
    atomicAdd(&cntS[s_idx[e]], 1);
    atomicAdd(&cntO[o_idx[e]], 1);
    atomicAdd(&cntC[c_idx[e]], 1);
}

__global__ __launch_bounds__(1024) void scan3_kernel(
        const int* __restrict__ cntS, const int* __restrict__ cntO,
        const int* __restrict__ cntC,
        int* __restrict__ startS, int* __restrict__ startO, int* __restrict__ startC) {
    const int* cnt; int* start; int n;
    if (blockIdx.x == 0)      { cnt = cntS; start = startS; n = NN; }
    else if (blockIdx.x == 1) { cnt = cntO; start = startO; n = NN; }
    else                      { cnt = cntC; start = startC; n = PP; }
    __shared__ int sh[1024];
    int t = threadIdx.x;
    int per = n >> 10;
    int base = t * per;
    int s = 0;
    for (int i = 0; i < per; i++) s += cnt[base + i];
    sh[t] = s;
    __syncthreads();
    for (int off = 1; off < 1024; off <<= 1) {
        int v = (t >= off) ? sh[t - off] : 0;
        __syncthreads();
        sh[t] += v;
        __syncthreads();
    }
    int ex = (t == 0) ? 0 : sh[t - 1];
    for (int i = 0; i < per; i++) { start[base + i] = ex; ex += cnt[base + i]; }
    if (t == 1023) start[n] = ex;
}

// ---------------------------------------------------------------------------
// Per-edge gates; computes CSR slot (scatter fused) and writes packed entries.
__global__ __launch_bounds__(256) void gate_kernel(
        const int* __restrict__ s_idx, const int* __restrict__ o_idx,
        const int* __restrict__ c_idx,
        const int* __restrict__ startS, const int* __restrict__ startO,
        const int* __restrict__ startC,
        int* __restrict__ curS, int* __restrict__ curO, int* __restrict__ curC,
        const ushort* __restrict__ Ti, const ushort* __restrict__ Tp,
        int2* __restrict__ pkS, int2* __restrict__ pkO, int4* __restrict__ pkC) {
    int gid = blockIdx.x * 256 + threadIdx.x;
    int e = gid >> 6, lane = gid & 63;
    if (e >= EE) return;
    int s = s_idx[e], o = o_idx[e], c = c_idx[e];
    const unsigned int* tpc = (const unsigned int*)(Tp + (size_t)c * G4);
    const unsigned int* tis = (const unsigned int*)(Ti + (size_t)s * G4);
    const unsigned int* tio = (const unsigned int*)(Ti + (size_t)o * G4);
    auto pairSig = [](unsigned int a, unsigned int b) {
        float lo = __uint_as_float(a << 16) + __uint_as_float(b << 16);
        float hi = __uint_as_float(a & 0xffff0000u) + __uint_as_float(b & 0xffff0000u);
        return sigmoid_relu(lo) + sigmoid_relu(hi);
    };
    float s0 = pairSig(tpc[lane],       tis[lane]);
    float s1 = pairSig(tpc[64 + lane],  tio[64 + lane]);
    float s2 = pairSig(tpc[128 + lane], tio[128 + lane]);
    float s3 = pairSig(tpc[192 + lane], tis[192 + lane]);
    #pragma unroll
    for (int off = 32; off; off >>= 1) {
        s0 += __shfl_xor(s0, off);
        s1 += __shfl_xor(s1, off);
        s2 += __shfl_xor(s2, off);
        s3 += __shfl_xor(s3, off);
    }
    if (lane == 0) {
        const float inv = 1.0f / 128.0f;
        int ps = startS[s] + atomicAdd(&curS[s], 1);
        int po = startO[o] + atomicAdd(&curO[o], 1);
        int pc = startC[c] + atomicAdd(&curC[c], 1);
        pkS[ps] = make_int2(c, __float_as_int(s0 * inv));
        pkO[po] = make_int2(c, __float_as_int(s1 * inv));
        pkC[pc] = make_int4(o, s, __float_as_int(s2 * inv), __float_as_int(s3 * inv));
    }
}

// ---------------------------------------------------------------------------
// Segment means, D-quartered and XCD-pinned for L2 residency.
// bid&7 = XCD; quarter q = xcd>>1 (3 MB working set per XCD pair, L2-fits);
// sub = (bid>>3)*2 + (xcd&1) enumerates the 3072 node-pairs per quarter.
__device__ __forceinline__ void accum4(float& a0, float& a1, float& a2, float& a3,
                                       uint2 v, float g) {
    a0 += g * lo16(v.x); a1 += g * hi16(v.x);
    a2 += g * lo16(v.y); a3 += g * hi16(v.y);
}

__global__ __launch_bounds__(256) void seg_kernel(
        const ushort* __restrict__ phraB, const ushort* __restrict__ instB,
        const int2* __restrict__ pkS, const int* __restrict__ startS,
        const int2* __restrict__ pkO, const int* __restrict__ startO,
        const int4* __restrict__ pkC, const int* __restrict__ startC,
        ushort* __restrict__ imsgB, ushort* __restrict__ pmsgB) {
    __shared__ float lds[4][64 * 5];
    int bid = blockIdx.x;
    int x = bid & 7;
    int q = x >> 1;
    int sub = ((bid >> 3) << 1) + (x & 1);
    int qoff = q * 256;
    int w = threadIdx.x >> 6, lane = threadIdx.x & 63;
    float a0 = 0.f, a1 = 0.f, a2 = 0.f, a3 = 0.f;
    bool instSide = sub < NN / 2;
    int segB, segE;
    ushort* msgB;
    int base2;
    if (instSide) {
        int node = sub * 2 + (w >> 1);
        const int2* pk_list = (w & 1) ? pkO : pkS;
        const int*  start   = (w & 1) ? startO : startS;
        int b = start[node], e = start[node + 1];
        if (b < e) {
            int2 pk = pk_list[b];
            uint2 v = *(const uint2*)(phraB + (size_t)pk.x * DD + qoff + lane * 4);
            for (int i = b + 1; i < e; i++) {
                int2 pkn = pk_list[i];
                uint2 vn = *(const uint2*)(phraB + (size_t)pkn.x * DD + qoff + lane * 4);
                accum4(a0, a1, a2, a3, v, __int_as_float(pk.y));
                pk = pkn; v = vn;
            }
            accum4(a0, a1, a2, a3, v, __int_as_float(pk.y));
        }
        segB = b; segE = e; msgB = imsgB; base2 = sub * 2;
    } else {
        int pbx = sub - NN / 2;
        int p = pbx * 2 + (w >> 1);
        int half = w & 1;
        int cb = startC[p], ce = startC[p + 1];
        int i0 = cb + half;
        if (i0 < ce) {
            int4 pk = pkC[i0];
            uint2 vo = *(const uint2*)(instB + (size_t)pk.x * DD + qoff + lane * 4);
            uint2 vs = *(const uint2*)(instB + (size_t)pk.y * DD + qoff + lane * 4);
            for (int i = i0 + 2; i < ce; i += 2) {
                int4 pkn = pkC[i];
                uint2 vno = *(const uint2*)(instB + (size_t)pkn.x * DD + qoff + lane * 4);
                uint2 vns = *(const uint2*)(instB + (size_t)pkn.y * DD + qoff + lane * 4);
                accum4(a0, a1, a2, a3, vo, __int_as_float(pk.z));
                accum4(a0, a1, a2, a3, vs, __int_as_float(pk.w));
                pk = pkn; vo = vno; vs = vns;
            }
            accum4(a0, a1, a2, a3, vo, __int_as_float(pk.z));
            accum4(a0, a1, a2, a3, vs, __int_as_float(pk.w));
        }
        segB = cb; segE = ce; msgB = pmsgB; base2 = pbx * 2;
    }
    float scale = 0.5f / (float)max(segE - segB, 1);
    lds[w][lane * 5 + 0] = a0 * scale;
    lds[w][lane * 5 + 1] = a1 * scale;
    lds[w][lane * 5 + 2] = a2 * scale;
    lds[w][lane * 5 + 3] = a3 * scale;
    __syncthreads();
    if (threadIdx.x < 128) {
        int node = threadIdx.x >> 6, l = threadIdx.x & 63;
        int w0 = node * 2;
        float s0 = lds[w0][l * 5 + 0] + lds[w0 + 1][l * 5 + 0];
        float s1 = lds[w0][l * 5 + 1] + lds[w0 + 1][l * 5 + 1];
        float s2 = lds[w0][l * 5 + 2] + lds[w0 + 1][l * 5 + 2];
        float s3 = lds[w0][l * 5 + 3] + lds[w0 + 1][l * 5 + 3];
        uint2 o;
        o.x = pack2(s0, s1);
        o.y = pack2(s2, s3);
        *(uint2*)&msgB[(size_t)(base2 + node) * DD + qoff + l * 4] = o;
    }
}

// ---------------------------------------------------------------------------
extern "C" void kernel_launch(void* const* d_in, const int* in_sizes, int n_in,
                              void* d_out, int out_size, void* d_ws, size_t ws_size,
                              hipStream_t stream) {
    (void)in_sizes; (void)n_in; (void)out_size; (void)ws_size;
    const float* inst_feat = (const float*)d_in[0];
    const float* phra_feat = (const float*)d_in[1];
    const int*   conn      = (const int*)d_in[2];
    const int*   clu       = (const int*)d_in[3];
    const float* psW = (const float*)d_in[4];  const float* psB = (const float*)d_in[5];
    const float* poW = (const float*)d_in[6];  const float* poB = (const float*)d_in[7];
    const float* opW = (const float*)d_in[8];  const float* opB = (const float*)d_in[9];
    const float* spW = (const float*)d_in[10]; const float* spB = (const float*)d_in[11];
    const float* iw1W = (const float*)d_in[12]; const float* iw1B = (const float*)d_in[13];
    const float* iw2W = (const float*)d_in[14]; const float* iw2B = (const float*)d_in[15];
    const float* pw1W = (const float*)d_in[16]; const float* pw1B = (const float*)d_in[17];
    const float* pw2W = (const float*)d_in[18]; const float* pw2B = (const float*)d_in[19];
    const int* s_idx = conn;
    const int* o_idx = conn + EE;

    char* ws = (char*)d_ws;
    size_t off = 0;
    auto alloc = [&](size_t bytes) {
        char* p = ws + off;
        off += (bytes + 255) & ~(size_t)255;
        return p;
    };
    ushort* instB = (ushort*)alloc((size_t)NN * DD * 2);
    ushort* phraB = (ushort*)alloc((size_t)PP * DD * 2);
    ushort* WiT   = (ushort*)alloc((size_t)G4 * DD * 2);
    ushort* WpT   = (ushort*)alloc((size_t)G4 * DD * 2);
    ushort* iw1T  = (ushort*)alloc((size_t)DD * DD * 2);
    ushort* iw2T  = (ushort*)alloc((size_t)DD * DD * 2);
    ushort* pw1T  = (ushort*)alloc((size_t)DD * DD * 2);
    ushort* pw2T  = (ushort*)alloc((size_t)DD * DD * 2);
    float* biascat = (float*)alloc(G4 * 4);
    ushort* TiB   = (ushort*)alloc((size_t)NN * G4 * 2);
    ushort* TpB   = (ushort*)alloc((size_t)PP * G4 * 2);
    int* cntBlock = (int*)alloc((size_t)NCNT * 4);
    int* cntS = cntBlock;      int* cntO = cntS + NN;  int* cntC = cntO + NN;
    int* curS = cntC + PP;     int* curO = curS + NN;  int* curC = curO + NN;
    int* startS = (int*)alloc((NN + 1) * 4);
    int* startO = (int*)alloc((NN + 1) * 4);
    int* startC = (int*)alloc((PP + 1) * 4);
    int2* pkS   = (int2*)alloc((size_t)EE * 8);
    int2* pkO   = (int2*)alloc((size_t)EE * 8);
    int4* pkC   = (int4*)alloc((size_t)EE * 16);
    ushort* imsgB = (ushort*)alloc((size_t)NN * DD * 2);
    ushort* pmsgB = (ushort*)alloc((size_t)PP * DD * 2);

    float* inst_out = (float*)d_out;
    float* phra_out = inst_out + (size_t)NN * DD;

    // Fused prep: counter zeroing + bf16 casts + weight pack/transpose
    prep_kernel<<<NB_ZERO + NB_F2B + NB_PACK + NB_WT, 256, 0, stream>>>(
        cntBlock, inst_feat, phra_feat, instB, phraB,
        psW, poW, opW, spW, psB, poB, opB, spB, WiT, WpT, biascat,
        iw1W, iw2W, pw1W, pw2W, iw1T, iw2T, pw1T, pw2T);

    // CSR build (scatter folded into gate_kernel)
    hist_kernel<<<EE / 256, 256, 0, stream>>>(s_idx, o_idx, clu, cntS, cntO, cntC);
    scan3_kernel<<<3, 1024, 0, stream>>>(cntS, cntO, cntC, startS, startO, startC);

    // Gate tables (bf16 MFMA, bias folded into Tp)
    mfma_tables_kernel<<<dim3((NN + PP) / 128, G4 / 64), 256, 0, stream>>>(
        instB, WiT, phraB, WpT, biascat, TiB, TpB);

    // Gates -> packed CSR entries (scatter fused)
    gate_kernel<<<(EE * 64) / 256, 256, 0, stream>>>(
        s_idx, o_idx, clu, startS, startO, startC, curS, curO, curC,
        TiB, TpB, pkS, pkO, pkC);

    // Segment means (D-quartered, XCD-pinned: 4 quarters x 3072 node-pairs)
    seg_kernel<<<(NN / 2 + PP / 2) * 4, 256, 0, stream>>>(
        phraB, instB, pkS, startS, pkO, startO, pkC, startC, imsgB, pmsgB);

    // Fused refine (128x64 tiles, 768 blocks, counted-vmcnt pipeline)
    mfma_refine_kernel<<<dim3((NN + PP) / 128, DD / 64), 256, 0, stream>>>(
        imsgB, instB, iw1T, iw2T, iw1B, iw2B, inst_out,
        pmsgB, phraB, pw1T, pw2T, pw1B, pw2B, phra_out);
}

// Round 9
// 156.911 us; speedup vs baseline: 1.1121x; 1.1121x over previous
//
#include <hip/hip_runtime.h>
#include <math.h>

// Problem constants (fixed by the reference)
constexpr int NN  = 4096;   // instances
constexpr int PP  = 2048;   // phrases
constexpr int EE  = 65536;  // edges
constexpr int DD  = 1024;   // feature dim
constexpr int OUTF = 128;   // gate MLP out dim
constexpr int G4  = 512;    // 4 gates * 128

typedef __attribute__((ext_vector_type(8))) short short8v;
typedef __attribute__((ext_vector_type(4))) float f32x4;

__device__ __forceinline__ float sigmoid_relu(float z) {
    z = fmaxf(z, 0.0f);
    return 1.0f / (1.0f + __expf(-z));
}
__device__ __forceinline__ float b2f(ushort u) {
    return __uint_as_float(((unsigned int)u) << 16);
}
__device__ __forceinline__ ushort f2b(float f) {  // RNE
    unsigned int x = __float_as_uint(f);
    return (ushort)((x + 0x7fffu + ((x >> 16) & 1u)) >> 16);
}
__device__ __forceinline__ unsigned int pack2(float a, float b) {
    return (unsigned int)f2b(a) | ((unsigned int)f2b(b) << 16);
}
__device__ __forceinline__ float lo16(unsigned int u) { return __uint_as_float(u << 16); }
__device__ __forceinline__ float hi16(unsigned int u) { return __uint_as_float(u & 0xffff0000u); }

#define GLD16(gptr, lptr) \
    __builtin_amdgcn_global_load_lds((__attribute__((address_space(1))) const void*)(gptr), \
                                     (__attribute__((address_space(3))) void*)(lptr), 16, 0, 0)
// Counted-vmcnt pipeline primitives (T4): keep just-issued loads in flight.
#define ASM_VMCNT(n) asm volatile("s_waitcnt vmcnt(" #n ")" ::: "memory")
#define BARRIER() do { asm volatile("" ::: "memory"); \
                       __builtin_amdgcn_s_barrier();  \
                       asm volatile("" ::: "memory"); } while (0)

// ---------------------------------------------------------------------------
// Fused prep: counter zeroing, f32->bf16 features, gate-weight pack,
// refine-weight transpose.
constexpr int NCNT    = 2 * (NN + NN + PP);        // 20480 ints (cnt + cur)
constexpr int NB_ZERO = NCNT / 256;                // 80
constexpr int NB_F2B  = (NN + PP) * DD / 4 / 256;  // 6144
constexpr int NB_PACK = G4 * DD / 256;             // 2048
constexpr int NB_WT   = 4 * (DD / 64) * (DD / 64); // 1024

__global__ __launch_bounds__(256) void prep_kernel(
        int* __restrict__ cntBlock,
        const float* __restrict__ instF, const float* __restrict__ phraF,
        ushort* __restrict__ instB, ushort* __restrict__ phraB,
        const float* __restrict__ psW, const float* __restrict__ poW,
        const float* __restrict__ opW, const float* __restrict__ spW,
        const float* __restrict__ psB, const float* __restrict__ poB,
        const float* __restrict__ opB, const float* __restrict__ spB,
        ushort* __restrict__ WiT, ushort* __restrict__ WpT,
        float* __restrict__ biascat,
        const float* __restrict__ W0, const float* __restrict__ W1,
        const float* __restrict__ W2, const float* __restrict__ W3,
        ushort* __restrict__ T0, ushort* __restrict__ T1,
        ushort* __restrict__ T2, ushort* __restrict__ T3) {
    __shared__ float tile[64][65];
    int b = blockIdx.x, t = threadIdx.x;
    if (b < NB_ZERO) {
        cntBlock[b * 256 + t] = 0;
        return;
    }
    b -= NB_ZERO;
    if (b < NB_F2B) {
        int i = b * 256 + t;
        constexpr int na4 = NN * DD / 4;
        if (i < na4) {
            float4 v = ((const float4*)instF)[i];
            ushort4 u; u.x = f2b(v.x); u.y = f2b(v.y); u.z = f2b(v.z); u.w = f2b(v.w);
            ((ushort4*)instB)[i] = u;
        } else {
            int j = i - na4;
            float4 v = ((const float4*)phraF)[j];
            ushort4 u; u.x = f2b(v.x); u.y = f2b(v.y); u.z = f2b(v.z); u.w = f2b(v.w);
            ((ushort4*)phraB)[j] = u;
        }
        return;
    }
    b -= NB_F2B;
    if (b < NB_PACK) {
        int idx = b * 256 + t;
        int n = idx >> 10, k = idx & 1023;
        int g = n >> 7, j = n & 127;
        float wi, wp;
        if (g == 0)      { wi = psW[(size_t)(DD + k) * OUTF + j]; wp = psW[(size_t)k * OUTF + j]; }
        else if (g == 1) { wi = poW[(size_t)(DD + k) * OUTF + j]; wp = poW[(size_t)k * OUTF + j]; }
        else if (g == 2) { wi = opW[(size_t)k * OUTF + j];        wp = opW[(size_t)(DD + k) * OUTF + j]; }
        else             { wi = spW[(size_t)k * OUTF + j];        wp = spW[(size_t)(DD + k) * OUTF + j]; }
        WiT[idx] = f2b(wi);
        WpT[idx] = f2b(wp);
        if (idx < G4) {
            int gg = idx >> 7, jj = idx & 127;
            biascat[idx] = (gg == 0) ? psB[jj] : (gg == 1) ? poB[jj]
                         : (gg == 2) ? opB[jj] : spB[jj];
        }
        return;
    }
    b -= NB_PACK;
    int z = b >> 8, rest = b & 255;
    const float* W = (z == 0) ? W0 : (z == 1) ? W1 : (z == 2) ? W2 : W3;
    ushort*      T = (z == 0) ? T0 : (z == 1) ? T1 : (z == 2) ? T2 : T3;
    int k0 = (rest & 15) * 64, n0 = (rest >> 4) * 64;
    int tx = t & 63, ty = t >> 6;
    #pragma unroll
    for (int i = 0; i < 64; i += 4)
        tile[ty + i][tx] = W[(size_t)(k0 + ty + i) * DD + n0 + tx];
    __syncthreads();
    #pragma unroll
    for (int i = 0; i < 64; i += 4)
        T[(size_t)(n0 + ty + i) * DD + k0 + tx] = f2b(tile[tx][ty + i]);
}

// ---------------------------------------------------------------------------
// Pipelined MFMA GEMM building blocks. A-tile 128 rows; B-tile BROWS rows.
// BK=64, XOR-swizzled linear LDS (rule 21).
template<int BROWS>
__device__ __forceinline__ void stage_tiles(const ushort* __restrict__ A,
                                            const ushort* __restrict__ BT,
                                            int bm, int bn, int k0,
                                            ushort* Asl, ushort* Bsl, int t) {
    #pragma unroll
    for (int r = 0; r < 4; r++) {
        int ch = r * 256 + t;
        int row = ch >> 3;
        int sw = ((ch & 7) ^ (row & 7)) << 3;
        GLD16(A + (size_t)(bm + row) * DD + k0 + sw, &Asl[ch * 8]);
    }
    #pragma unroll
    for (int r = 0; r < BROWS / 32; r++) {
        int ch = r * 256 + t;
        int row = ch >> 3;
        int sw = ((ch & 7) ^ (row & 7)) << 3;
        GLD16(BT + (size_t)(bn + row) * DD + k0 + sw, &Bsl[ch * 8]);
    }
}

template<int NACC>
__device__ __forceinline__ void compute_tiles(const ushort* Asl, const ushort* Bsl,
                                              f32x4 (&acc)[4][NACC],
                                              int wr, int wc, int lr, int lk) {
    #pragma unroll
    for (int kk = 0; kk < 2; kk++) {
        int ch16 = kk * 4 + lk;
        short8v a[4], b[NACC];
        #pragma unroll
        for (int m = 0; m < 4; m++) {
            int ra = wr + m * 16 + lr;
            a[m] = *(const short8v*)&Asl[ra * 64 + ((ch16 ^ (ra & 7)) << 3)];
        }
        #pragma unroll
        for (int n = 0; n < NACC; n++) {
            int rb = wc + n * 16 + lr;
            b[n] = *(const short8v*)&Bsl[rb * 64 + ((ch16 ^ (rb & 7)) << 3)];
        }
        #pragma unroll
        for (int m = 0; m < 4; m++)
            #pragma unroll
            for (int n = 0; n < NACC; n++)
                acc[m][n] = __builtin_amdgcn_mfma_f32_16x16x32_bf16(a[m], b[n], acc[m][n], 0, 0, 0);
    }
}

// ---------------------------------------------------------------------------
// Gate tables, 128x64 tile, counted-vmcnt 2-buffer pipeline.
__global__ __launch_bounds__(256) void mfma_tables_kernel(
        const ushort* __restrict__ instB, const ushort* __restrict__ WiT,
        const ushort* __restrict__ phraB, const ushort* __restrict__ WpT,
        const float* __restrict__ biascat,
        ushort* __restrict__ TiB, ushort* __restrict__ TpB) {
    __shared__ ushort Asl[2][128 * 64];
    __shared__ ushort Bsl[2][64 * 64];
    int bx = blockIdx.x;
    const ushort *A, *BT; ushort* C; const float* bias;
    if (bx < NN / 128) { A = instB; BT = WiT; C = TiB; bias = nullptr; }
    else { bx -= NN / 128; A = phraB; BT = WpT; C = TpB; bias = biascat; }
    int bm = bx * 128, bn = blockIdx.y * 64;
    int t = threadIdx.x;
    const int lane = t & 63, w = t >> 6;
    const int wr = (w >> 1) * 64, wc = (w & 1) * 32;
    const int lr = lane & 15, lk = lane >> 4;
    f32x4 acc[4][2] = {};

    int cur = 0;
    stage_tiles<64>(A, BT, bm, bn, 0, Asl[0], Bsl[0], t);
    for (int k0 = 0; k0 < DD; k0 += 64) {
        int nxt = cur ^ 1;
        if (k0 + 64 < DD) {
            stage_tiles<64>(A, BT, bm, bn, k0 + 64, Asl[nxt], Bsl[nxt], t);
            ASM_VMCNT(6);
        } else {
            ASM_VMCNT(0);
        }
        BARRIER();
        compute_tiles<2>(Asl[cur], Bsl[cur], acc, wr, wc, lr, lk);
        BARRIER();
        cur = nxt;
    }
    #pragma unroll
    for (int m = 0; m < 4; m++) {
        int row = bm + wr + m * 16 + lk * 4;
        #pragma unroll
        for (int n = 0; n < 2; n++) {
            int col = bn + wc + n * 16 + lr;
            float bv = bias ? bias[col] : 0.f;
            #pragma unroll
            for (int r = 0; r < 4; r++)
                C[(size_t)(row + r) * G4 + col] = f2b(acc[m][n][r] + bv);
        }
    }
}

// ---------------------------------------------------------------------------
// Fused refine: out = msg + relu(msg@W1+b1) + relu(feat@W2+b2).
// 128x64 tile (768 blocks), continuous counted-vmcnt pipeline.
__global__ __launch_bounds__(256) void mfma_refine_kernel(
        const ushort* __restrict__ imsgB, const ushort* __restrict__ instB,
        const ushort* __restrict__ iw1T, const ushort* __restrict__ iw2T,
        const float* __restrict__ ib1, const float* __restrict__ ib2,
        float* __restrict__ iout,
        const ushort* __restrict__ pmsgB, const ushort* __restrict__ phraB,
        const ushort* __restrict__ pw1T, const ushort* __restrict__ pw2T,
        const float* __restrict__ pb1, const float* __restrict__ pb2,
        float* __restrict__ pout) {
    __shared__ ushort Asl[2][128 * 64];
    __shared__ ushort Bsl[2][64 * 64];
    int bx = blockIdx.x;
    const ushort *Am, *Af, *W1, *W2; const float *b1, *b2; float* out;
    if (bx < NN / 128) {
        Am = imsgB; Af = instB; W1 = iw1T; W2 = iw2T; b1 = ib1; b2 = ib2; out = iout;
    } else {
        bx -= NN / 128;
        Am = pmsgB; Af = phraB; W1 = pw1T; W2 = pw2T; b1 = pb1; b2 = pb2; out = pout;
    }
    int bm = bx * 128, bn = blockIdx.y * 64;
    int t = threadIdx.x;
    const int lane = t & 63, w = t >> 6;
    const int wr = (w >> 1) * 64, wc = (w & 1) * 32;
    const int lr = lane & 15, lk = lane >> 4;
    f32x4 acc1[4][2] = {};
    f32x4 acc2[4][2] = {};

    int cur = 0;
    stage_tiles<64>(Am, W1, bm, bn, 0, Asl[0], Bsl[0], t);
    auto run = [&](const ushort* A, const ushort* B, f32x4 (&acc)[4][2],
                   const ushort* An, const ushort* Bn) {
        for (int k0 = 0; k0 < DD; k0 += 64) {
            int nxt = cur ^ 1;
            if (k0 + 64 < DD) {
                stage_tiles<64>(A, B, bm, bn, k0 + 64, Asl[nxt], Bsl[nxt], t);
                ASM_VMCNT(6);
            } else if (An) {
                stage_tiles<64>(An, Bn, bm, bn, 0, Asl[nxt], Bsl[nxt], t);
                ASM_VMCNT(6);
            } else {
                ASM_VMCNT(0);
            }
            BARRIER();
            compute_tiles<2>(Asl[cur], Bsl[cur], acc, wr, wc, lr, lk);
            BARRIER();
            cur = nxt;
        }
    };
    run(Am, W1, acc1, Af, W2);
    run(Af, W2, acc2, nullptr, nullptr);

    #pragma unroll
    for (int m = 0; m < 4; m++) {
        int row = bm + wr + m * 16 + lk * 4;
        #pragma unroll
        for (int n = 0; n < 2; n++) {
            int col = bn + wc + n * 16 + lr;
            float vb1 = b1[col], vb2 = b2[col];
            #pragma unroll
            for (int r = 0; r < 4; r++) {
                float v = b2f(Am[(size_t)(row + r) * DD + col])
                        + fmaxf(acc1[m][n][r] + vb1, 0.f)
                        + fmaxf(acc2[m][n][r] + vb2, 0.f);
                out[(size_t)(row + r) * DD + col] = v;
            }
        }
    }
}

// ---------------------------------------------------------------------------
// Counting sort: histogram + scan (scatter is folded into gate_kernel).
__global__ void hist_kernel(const int* __restrict__ s_idx, const int* __restrict__ o_idx,
                            const int* __restrict__ c_idx,
                            int* cntS, int* cntO, int* cntC) {
    int e = blockIdx.x * blockDim.x + threadIdx.x;
    if (e >= EE) return;
    atomicAdd(&cntS[s_idx[e]], 1);
    atomicAdd(&cntO[o_idx[e]], 1);
    atomicAdd(&cntC[c_idx[e]], 1);
}

__global__ __launch_bounds__(1024) void scan3_kernel(
        const int* __restrict__ cntS, const int* __restrict__ cntO,
        const int* __restrict__ cntC,
        int* __restrict__ startS, int* __restrict__ startO, int* __restrict__ startC) {
    const int* cnt; int* start; int n;
    if (blockIdx.x == 0)      { cnt = cntS; start = startS; n = NN; }
    else if (blockIdx.x == 1) { cnt = cntO; start = startO; n = NN; }
    else                      { cnt = cntC; start = startC; n = PP; }
    __shared__ int sh[1024];
    int t = threadIdx.x;
    int per = n >> 10;
    int base = t * per;
    int s = 0;
    for (int i = 0; i < per; i++) s += cnt[base + i];
    sh[t] = s;
    __syncthreads();
    for (int off = 1; off < 1024; off <<= 1) {
        int v = (t >= off) ? sh[t - off] : 0;
        __syncthreads();
        sh[t] += v;
        __syncthreads();
    }
    int ex = (t == 0) ? 0 : sh[t - 1];
    for (int i = 0; i < per; i++) { start[base + i] = ex; ex += cnt[base + i]; }
    if (t == 1023) start[n] = ex;
}

// ---------------------------------------------------------------------------
// Per-edge gates; computes CSR slot (scatter fused) and writes packed entries.
__global__ __launch_bounds__(256) void gate_kernel(
        const int* __restrict__ s_idx, const int* __restrict__ o_idx,
        const int* __restrict__ c_idx,
        const int* __restrict__ startS, const int* __restrict__ startO,
        const int* __restrict__ startC,
        int* __restrict__ curS, int* __restrict__ curO, int* __restrict__ curC,
        const ushort* __restrict__ Ti, const ushort* __restrict__ Tp,
        int2* __restrict__ pkS, int2* __restrict__ pkO, int4* __restrict__ pkC) {
    int gid = blockIdx.x * 256 + threadIdx.x;
    int e = gid >> 6, lane = gid & 63;
    if (e >= EE) return;
    int s = s_idx[e], o = o_idx[e], c = c_idx[e];
    const unsigned int* tpc = (const unsigned int*)(Tp + (size_t)c * G4);
    const unsigned int* tis = (const unsigned int*)(Ti + (size_t)s * G4);
    const unsigned int* tio = (const unsigned int*)(Ti + (size_t)o * G4);
    auto pairSig = [](unsigned int a, unsigned int b) {
        float lo = __uint_as_float(a << 16) + __uint_as_float(b << 16);
        float hi = __uint_as_float(a & 0xffff0000u) + __uint_as_float(b & 0xffff0000u);
        return sigmoid_relu(lo) + sigmoid_relu(hi);
    };
    float s0 = pairSig(tpc[lane],       tis[lane]);
    float s1 = pairSig(tpc[64 + lane],  tio[64 + lane]);
    float s2 = pairSig(tpc[128 + lane], tio[128 + lane]);
    float s3 = pairSig(tpc[192 + lane], tis[192 + lane]);
    #pragma unroll
    for (int off = 32; off; off >>= 1) {
        s0 += __shfl_xor(s0, off);
        s1 += __shfl_xor(s1, off);
        s2 += __shfl_xor(s2, off);
        s3 += __shfl_xor(s3, off);
    }
    if (lane == 0) {
        const float inv = 1.0f / 128.0f;
        int ps = startS[s] + atomicAdd(&curS[s], 1);
        int po = startO[o] + atomicAdd(&curO[o], 1);
        int pc = startC[c] + atomicAdd(&curC[c], 1);
        pkS[ps] = make_int2(c, __float_as_int(s0 * inv));
        pkO[po] = make_int2(c, __float_as_int(s1 * inv));
        pkC[pc] = make_int4(o, s, __float_as_int(s2 * inv), __float_as_int(s3 * inv));
    }
}

// ---------------------------------------------------------------------------
// Segment means, D-quartered + XCD-pinned (traffic win proven in R8:
// FETCH 106->17.5 MB).  R9 fix: pk entries are bulk-loaded 64-at-a-time into
// lane registers with ONE coalesced load and broadcast via __shfl
// (ds_bpermute -> lgkmcnt), so the row-load loop has exactly one VMEM op per
// iteration and the accumulate wait compiles to vmcnt(1) instead of a full
// pipeline drain (R8's pk->row dependent chain drained all in-flight rows).
__global__ __launch_bounds__(256) void seg_kernel(
        const ushort* __restrict__ phraB, const ushort* __restrict__ instB,
        const int2* __restrict__ pkS, const int* __restrict__ startS,
        const int2* __restrict__ pkO, const int* __restrict__ startO,
        const int4* __restrict__ pkC, const int* __restrict__ startC,
        ushort* __restrict__ imsgB, ushort* __restrict__ pmsgB) {
    __shared__ float lds[4][64 * 5];
    int bid = blockIdx.x;
    int x = bid & 7;
    int q = x >> 1;
    int sub = ((bid >> 3) << 1) + (x & 1);
    int qoff = q * 256;
    int w = threadIdx.x >> 6, lane = threadIdx.x & 63;
    float a0 = 0.f, a1 = 0.f, a2 = 0.f, a3 = 0.f;
    bool instSide = sub < NN / 2;
    int lenScale;
    ushort* msgB;
    int base2;
    if (instSide) {
        int node = sub * 2 + (w >> 1);
        const int2* pk_list = (w & 1) ? pkO : pkS;
        const int*  start   = (w & 1) ? startO : startS;
        int b = start[node], e = start[node + 1];
        lenScale = e - b;
        for (int base = b; base < e; base += 64) {
            int n = min(64, e - base);
            int2 pkv = pk_list[base + min(lane, n - 1)];   // one coalesced load
            int   cj = __shfl(pkv.x, 0);
            float gj = __int_as_float(__shfl(pkv.y, 0));
            uint2 v = *(const uint2*)(phraB + (size_t)cj * DD + qoff + lane * 4);
            for (int j = 1; j < n; j++) {
                int   cn = __shfl(pkv.x, j);
                float gn = __int_as_float(__shfl(pkv.y, j));
                uint2 vn = *(const uint2*)(phraB + (size_t)cn * DD + qoff + lane * 4);
                a0 += gj * lo16(v.x); a1 += gj * hi16(v.x);
                a2 += gj * lo16(v.y); a3 += gj * hi16(v.y);
                v = vn; gj = gn;
            }
            a0 += gj * lo16(v.x); a1 += gj * hi16(v.x);
            a2 += gj * lo16(v.y); a3 += gj * hi16(v.y);
        }
        msgB = imsgB; base2 = sub * 2;
    } else {
        int pbx = sub - NN / 2;
        int p = pbx * 2 + (w >> 1);
        int cb = startC[p], ce = startC[p + 1];
        lenScale = ce - cb;
        int mid = cb + ((ce - cb) >> 1);
        int mb = (w & 1) ? mid : cb;       // contiguous halves (coalesced chunks)
        int me = (w & 1) ? ce : mid;
        for (int base = mb; base < me; base += 64) {
            int n = min(64, me - base);
            int4 pkv = pkC[base + min(lane, n - 1)];
            int   oj = __shfl(pkv.x, 0), sj = __shfl(pkv.y, 0);
            float goj = __int_as_float(__shfl(pkv.z, 0));
            float gsj = __int_as_float(__shfl(pkv.w, 0));
            uint2 vo = *(const uint2*)(instB + (size_t)oj * DD + qoff + lane * 4);
            uint2 vs = *(const uint2*)(instB + (size_t)sj * DD + qoff + lane * 4);
            for (int j = 1; j < n; j++) {
                int   on = __shfl(pkv.x, j), sn = __shfl(pkv.y, j);
                float gon = __int_as_float(__shfl(pkv.z, j));
                float gsn = __int_as_float(__shfl(pkv.w, j));
                uint2 vno = *(const uint2*)(instB + (size_t)on * DD + qoff + lane * 4);
                uint2 vns = *(const uint2*)(instB + (size_t)sn * DD + qoff + lane * 4);
                a0 += goj * lo16(vo.x) + gsj * lo16(vs.x);
                a1 += goj * hi16(vo.x) + gsj * hi16(vs.x);
                a2 += goj * lo16(vo.y) + gsj * lo16(vs.y);
                a3 += goj * hi16(vo.y) + gsj * hi16(vs.y);
                vo = vno; vs = vns; goj = gon; gsj = gsn;
            }
            a0 += goj * lo16(vo.x) + gsj * lo16(vs.x);
            a1 += goj * hi16(vo.x) + gsj * hi16(vs.x);
            a2 += goj * lo16(vo.y) + gsj * lo16(vs.y);
            a3 += goj * hi16(vo.y) + gsj * hi16(vs.y);
        }
        msgB = pmsgB; base2 = pbx * 2;
    }
    float scale = 0.5f / (float)max(lenScale, 1);
    lds[w][lane * 5 + 0] = a0 * scale;
    lds[w][lane * 5 + 1] = a1 * scale;
    lds[w][lane * 5 + 2] = a2 * scale;
    lds[w][lane * 5 + 3] = a3 * scale;
    __syncthreads();
    if (threadIdx.x < 128) {
        int node = threadIdx.x >> 6, l = threadIdx.x & 63;
        int w0 = node * 2;
        float s0 = lds[w0][l * 5 + 0] + lds[w0 + 1][l * 5 + 0];
        float s1 = lds[w0][l * 5 + 1] + lds[w0 + 1][l * 5 + 1];
        float s2 = lds[w0][l * 5 + 2] + lds[w0 + 1][l * 5 + 2];
        float s3 = lds[w0][l * 5 + 3] + lds[w0 + 1][l * 5 + 3];
        uint2 o;
        o.x = pack2(s0, s1);
        o.y = pack2(s2, s3);
        *(uint2*)&msgB[(size_t)(base2 + node) * DD + qoff + l * 4] = o;
    }
}

// ---------------------------------------------------------------------------
extern "C" void kernel_launch(void* const* d_in, const int* in_sizes, int n_in,
                              void* d_out, int out_size, void* d_ws, size_t ws_size,
                              hipStream_t stream) {
    (void)in_sizes; (void)n_in; (void)out_size; (void)ws_size;
    const float* inst_feat = (const float*)d_in[0];
    const float* phra_feat = (const float*)d_in[1];
    const int*   conn      = (const int*)d_in[2];
    const int*   clu       = (const int*)d_in[3];
    const float* psW = (const float*)d_in[4];  const float* psB = (const float*)d_in[5];
    const float* poW = (const float*)d_in[6];  const float* poB = (const float*)d_in[7];
    const float* opW = (const float*)d_in[8];  const float* opB = (const float*)d_in[9];
    const float* spW = (const float*)d_in[10]; const float* spB = (const float*)d_in[11];
    const float* iw1W = (const float*)d_in[12]; const float* iw1B = (const float*)d_in[13];
    const float* iw2W = (const float*)d_in[14]; const float* iw2B = (const float*)d_in[15];
    const float* pw1W = (const float*)d_in[16]; const float* pw1B = (const float*)d_in[17];
    const float* pw2W = (const float*)d_in[18]; const float* pw2B = (const float*)d_in[19];
    const int* s_idx = conn;
    const int* o_idx = conn + EE;

    char* ws = (char*)d_ws;
    size_t off = 0;
    auto alloc = [&](size_t bytes) {
        char* p = ws + off;
        off += (bytes + 255) & ~(size_t)255;
        return p;
    };
    ushort* instB = (ushort*)alloc((size_t)NN * DD * 2);
    ushort* phraB = (ushort*)alloc((size_t)PP * DD * 2);
    ushort* WiT   = (ushort*)alloc((size_t)G4 * DD * 2);
    ushort* WpT   = (ushort*)alloc((size_t)G4 * DD * 2);
    ushort* iw1T  = (ushort*)alloc((size_t)DD * DD * 2);
    ushort* iw2T  = (ushort*)alloc((size_t)DD * DD * 2);
    ushort* pw1T  = (ushort*)alloc((size_t)DD * DD * 2);
    ushort* pw2T  = (ushort*)alloc((size_t)DD * DD * 2);
    float* biascat = (float*)alloc(G4 * 4);
    ushort* TiB   = (ushort*)alloc((size_t)NN * G4 * 2);
    ushort* TpB   = (ushort*)alloc((size_t)PP * G4 * 2);
    int* cntBlock = (int*)alloc((size_t)NCNT * 4);
    int* cntS = cntBlock;      int* cntO = cntS + NN;  int* cntC = cntO + NN;
    int* curS = cntC + PP;     int* curO = curS + NN;  int* curC = curO + NN;
    int* startS = (int*)alloc((NN + 1) * 4);
    int* startO = (int*)alloc((NN + 1) * 4);
    int* startC = (int*)alloc((PP + 1) * 4);
    int2* pkS   = (int2*)alloc((size_t)EE * 8);
    int2* pkO   = (int2*)alloc((size_t)EE * 8);
    int4* pkC   = (int4*)alloc((size_t)EE * 16);
    ushort* imsgB = (ushort*)alloc((size_t)NN * DD * 2);
    ushort* pmsgB = (ushort*)alloc((size_t)PP * DD * 2);

    float* inst_out = (float*)d_out;
    float* phra_out = inst_out + (size_t)NN * DD;

    // Fused prep: counter zeroing + bf16 casts + weight pack/transpose
    prep_kernel<<<NB_ZERO + NB_F2B + NB_PACK + NB_WT, 256, 0, stream>>>(
        cntBlock, inst_feat, phra_feat, instB, phraB,
        psW, poW, opW, spW, psB, poB, opB, spB, WiT, WpT, biascat,
        iw1W, iw2W, pw1W, pw2W, iw1T, iw2T, pw1T, pw2T);

    // CSR build (scatter folded into gate_kernel)
    hist_kernel<<<EE / 256, 256, 0, stream>>>(s_idx, o_idx, clu, cntS, cntO, cntC);
    scan3_kernel<<<3, 1024, 0, stream>>>(cntS, cntO, cntC, startS, startO, startC);

    // Gate tables (bf16 MFMA, bias folded into Tp)
    mfma_tables_kernel<<<dim3((NN + PP) / 128, G4 / 64), 256, 0, stream>>>(
        instB, WiT, phraB, WpT, biascat, TiB, TpB);

    // Gates -> packed CSR entries (scatter fused)
    gate_kernel<<<(EE * 64) / 256, 256, 0, stream>>>(
        s_idx, o_idx, clu, startS, startO, startC, curS, curO, curC,
        TiB, TpB, pkS, pkO, pkC);

    // Segment means (D-quartered, XCD-pinned, shfl-broadcast pk pipeline)
    seg_kernel<<<(NN / 2 + PP / 2) * 4, 256, 0, stream>>>(
        phraB, instB, pkS, startS, pkO, startO, pkC, startC, imsgB, pmsgB);

    // Fused refine (128x64 tiles, 768 blocks, counted-vmcnt pipeline)
    mfma_refine_kernel<<<dim3((NN + PP) / 128, DD / 64), 256, 0, stream>>>(
        imsgB, instB, iw1T, iw2T, iw1B, iw2B, inst_out,
        pmsgB, phraB, pw1T, pw2T, pw1B, pw2B, phra_out);
}

// Round 10
// 148.323 us; speedup vs baseline: 1.1765x; 1.0579x over previous
//
#include <hip/hip_runtime.h>
#include <math.h>

// Problem constants (fixed by the reference)
constexpr int NN  = 4096;   // instances
constexpr int PP  = 2048;   // phrases
constexpr int EE  = 65536;  // edges
constexpr int DD  = 1024;   // feature dim
constexpr int OUTF = 128;   // gate MLP out dim
constexpr int G4  = 512;    // 4 gates * 128

typedef __attribute__((ext_vector_type(8))) short short8v;
typedef __attribute__((ext_vector_type(4))) float f32x4;

__device__ __forceinline__ float sigmoid_relu(float z) {
    z = fmaxf(z, 0.0f);
    return 1.0f / (1.0f + __expf(-z));
}
__device__ __forceinline__ float b2f(ushort u) {
    return __uint_as_float(((unsigned int)u) << 16);
}
__device__ __forceinline__ ushort f2b(float f) {  // RNE
    unsigned int x = __float_as_uint(f);
    return (ushort)((x + 0x7fffu + ((x >> 16) & 1u)) >> 16);
}
__device__ __forceinline__ unsigned int pack2(float a, float b) {
    return (unsigned int)f2b(a) | ((unsigned int)f2b(b) << 16);
}
__device__ __forceinline__ float lo16(unsigned int u) { return __uint_as_float(u << 16); }
__device__ __forceinline__ float hi16(unsigned int u) { return __uint_as_float(u & 0xffff0000u); }

#define GLD16(gptr, lptr) \
    __builtin_amdgcn_global_load_lds((__attribute__((address_space(1))) const void*)(gptr), \
                                     (__attribute__((address_space(3))) void*)(lptr), 16, 0, 0)
// Counted-vmcnt pipeline primitives (T4): keep just-issued loads in flight.
#define ASM_VMCNT(n) asm volatile("s_waitcnt vmcnt(" #n ")" ::: "memory")
#define BARRIER() do { asm volatile("" ::: "memory"); \
                       __builtin_amdgcn_s_barrier();  \
                       asm volatile("" ::: "memory"); } while (0)

// ---------------------------------------------------------------------------
// Fused prep: counter zeroing, f32->bf16 features, gate-weight pack,
// refine-weight transpose.
constexpr int NCNT    = 2 * (NN + NN + PP);        // 20480 ints (cnt + cur)
constexpr int NB_ZERO = NCNT / 256;                // 80
constexpr int NB_F2B  = (NN + PP) * DD / 4 / 256;  // 6144
constexpr int NB_PACK = G4 * DD / 256;             // 2048
constexpr int NB_WT   = 4 * (DD / 64) * (DD / 64); // 1024

__global__ __launch_bounds__(256) void prep_kernel(
        int* __restrict__ cntBlock,
        const float* __restrict__ instF, const float* __restrict__ phraF,
        ushort* __restrict__ instB, ushort* __restrict__ phraB,
        const float* __restrict__ psW, const float* __restrict__ poW,
        const float* __restrict__ opW, const float* __restrict__ spW,
        const float* __restrict__ psB, const float* __restrict__ poB,
        const float* __restrict__ opB, const float* __restrict__ spB,
        ushort* __restrict__ WiT, ushort* __restrict__ WpT,
        float* __restrict__ biascat,
        const float* __restrict__ W0, const float* __restrict__ W1,
        const float* __restrict__ W2, const float* __restrict__ W3,
        ushort* __restrict__ T0, ushort* __restrict__ T1,
        ushort* __restrict__ T2, ushort* __restrict__ T3) {
    __shared__ float tile[64][65];
    int b = blockIdx.x, t = threadIdx.x;
    if (b < NB_ZERO) {
        cntBlock[b * 256 + t] = 0;
        return;
    }
    b -= NB_ZERO;
    if (b < NB_F2B) {
        int i = b * 256 + t;
        constexpr int na4 = NN * DD / 4;
        if (i < na4) {
            float4 v = ((const float4*)instF)[i];
            ushort4 u; u.x = f2b(v.x); u.y = f2b(v.y); u.z = f2b(v.z); u.w = f2b(v.w);
            ((ushort4*)instB)[i] = u;
        } else {
            int j = i - na4;
            float4 v = ((const float4*)phraF)[j];
            ushort4 u; u.x = f2b(v.x); u.y = f2b(v.y); u.z = f2b(v.z); u.w = f2b(v.w);
            ((ushort4*)phraB)[j] = u;
        }
        return;
    }
    b -= NB_F2B;
    if (b < NB_PACK) {
        int idx = b * 256 + t;
        int n = idx >> 10, k = idx & 1023;
        int g = n >> 7, j = n & 127;
        float wi, wp;
        if (g == 0)      { wi = psW[(size_t)(DD + k) * OUTF + j]; wp = psW[(size_t)k * OUTF + j]; }
        else if (g == 1) { wi = poW[(size_t)(DD + k) * OUTF + j]; wp = poW[(size_t)k * OUTF + j]; }
        else if (g == 2) { wi = opW[(size_t)k * OUTF + j];        wp = opW[(size_t)(DD + k) * OUTF + j]; }
        else             { wi = spW[(size_t)k * OUTF + j];        wp = spW[(size_t)(DD + k) * OUTF + j]; }
        WiT[idx] = f2b(wi);
        WpT[idx] = f2b(wp);
        if (idx < G4) {
            int gg = idx >> 7, jj = idx & 127;
            biascat[idx] = (gg == 0) ? psB[jj] : (gg == 1) ? poB[jj]
                         : (gg == 2) ? opB[jj] : spB[jj];
        }
        return;
    }
    b -= NB_PACK;
    int z = b >> 8, rest = b & 255;
    const float* W = (z == 0) ? W0 : (z == 1) ? W1 : (z == 2) ? W2 : W3;
    ushort*      T = (z == 0) ? T0 : (z == 1) ? T1 : (z == 2) ? T2 : T3;
    int k0 = (rest & 15) * 64, n0 = (rest >> 4) * 64;
    int tx = t & 63, ty = t >> 6;
    #pragma unroll
    for (int i = 0; i < 64; i += 4)
        tile[ty + i][tx] = W[(size_t)(k0 + ty + i) * DD + n0 + tx];
    __syncthreads();
    #pragma unroll
    for (int i = 0; i < 64; i += 4)
        T[(size_t)(n0 + ty + i) * DD + k0 + tx] = f2b(tile[tx][ty + i]);
}

// ---------------------------------------------------------------------------
// Pipelined MFMA GEMM building blocks. A-tile 128 rows; B-tile BROWS rows.
// BK=64, XOR-swizzled linear LDS (rule 21).
template<int BROWS>
__device__ __forceinline__ void stage_tiles(const ushort* __restrict__ A,
                                            const ushort* __restrict__ BT,
                                            int bm, int bn, int k0,
                                            ushort* Asl, ushort* Bsl, int t) {
    #pragma unroll
    for (int r = 0; r < 4; r++) {
        int ch = r * 256 + t;
        int row = ch >> 3;
        int sw = ((ch & 7) ^ (row & 7)) << 3;
        GLD16(A + (size_t)(bm + row) * DD + k0 + sw, &Asl[ch * 8]);
    }
    #pragma unroll
    for (int r = 0; r < BROWS / 32; r++) {
        int ch = r * 256 + t;
        int row = ch >> 3;
        int sw = ((ch & 7) ^ (row & 7)) << 3;
        GLD16(BT + (size_t)(bn + row) * DD + k0 + sw, &Bsl[ch * 8]);
    }
}

template<int NACC>
__device__ __forceinline__ void compute_tiles(const ushort* Asl, const ushort* Bsl,
                                              f32x4 (&acc)[4][NACC],
                                              int wr, int wc, int lr, int lk) {
    #pragma unroll
    for (int kk = 0; kk < 2; kk++) {
        int ch16 = kk * 4 + lk;
        short8v a[4], b[NACC];
        #pragma unroll
        for (int m = 0; m < 4; m++) {
            int ra = wr + m * 16 + lr;
            a[m] = *(const short8v*)&Asl[ra * 64 + ((ch16 ^ (ra & 7)) << 3)];
        }
        #pragma unroll
        for (int n = 0; n < NACC; n++) {
            int rb = wc + n * 16 + lr;
            b[n] = *(const short8v*)&Bsl[rb * 64 + ((ch16 ^ (rb & 7)) << 3)];
        }
        #pragma unroll
        for (int m = 0; m < 4; m++)
            #pragma unroll
            for (int n = 0; n < NACC; n++)
                acc[m][n] = __builtin_amdgcn_mfma_f32_16x16x32_bf16(a[m], b[n], acc[m][n], 0, 0, 0);
    }
}

// ---------------------------------------------------------------------------
// Gate tables, 128x64 tile, counted-vmcnt 2-buffer pipeline.
__global__ __launch_bounds__(256) void mfma_tables_kernel(
        const ushort* __restrict__ instB, const ushort* __restrict__ WiT,
        const ushort* __restrict__ phraB, const ushort* __restrict__ WpT,
        const float* __restrict__ biascat,
        ushort* __restrict__ TiB, ushort* __restrict__ TpB) {
    __shared__ ushort Asl[2][128 * 64];
    __shared__ ushort Bsl[2][64 * 64];
    int bx = blockIdx.x;
    const ushort *A, *BT; ushort* C; const float* bias;
    if (bx < NN / 128) { A = instB; BT = WiT; C = TiB; bias = nullptr; }
    else { bx -= NN / 128; A = phraB; BT = WpT; C = TpB; bias = biascat; }
    int bm = bx * 128, bn = blockIdx.y * 64;
    int t = threadIdx.x;
    const int lane = t & 63, w = t >> 6;
    const int wr = (w >> 1) * 64, wc = (w & 1) * 32;
    const int lr = lane & 15, lk = lane >> 4;
    f32x4 acc[4][2] = {};

    int cur = 0;
    stage_tiles<64>(A, BT, bm, bn, 0, Asl[0], Bsl[0], t);
    for (int k0 = 0; k0 < DD; k0 += 64) {
        int nxt = cur ^ 1;
        if (k0 + 64 < DD) {
            stage_tiles<64>(A, BT, bm, bn, k0 + 64, Asl[nxt], Bsl[nxt], t);
            ASM_VMCNT(6);
        } else {
            ASM_VMCNT(0);
        }
        BARRIER();
        compute_tiles<2>(Asl[cur], Bsl[cur], acc, wr, wc, lr, lk);
        BARRIER();
        cur = nxt;
    }
    #pragma unroll
    for (int m = 0; m < 4; m++) {
        int row = bm + wr + m * 16 + lk * 4;
        #pragma unroll
        for (int n = 0; n < 2; n++) {
            int col = bn + wc + n * 16 + lr;
            float bv = bias ? bias[col] : 0.f;
            #pragma unroll
            for (int r = 0; r < 4; r++)
                C[(size_t)(row + r) * G4 + col] = f2b(acc[m][n][r] + bv);
        }
    }
}

// ---------------------------------------------------------------------------
// Fused refine: out = msg + relu(msg@W1+b1) + relu(feat@W2+b2).
// 128x64 tile (768 blocks), continuous counted-vmcnt pipeline.
__global__ __launch_bounds__(256) void mfma_refine_kernel(
        const ushort* __restrict__ imsgB, const ushort* __restrict__ instB,
        const ushort* __restrict__ iw1T, const ushort* __restrict__ iw2T,
        const float* __restrict__ ib1, const float* __restrict__ ib2,
        float* __restrict__ iout,
        const ushort* __restrict__ pmsgB, const ushort* __restrict__ phraB,
        const ushort* __restrict__ pw1T, const ushort* __restrict__ pw2T,
        const float* __restrict__ pb1, const float* __restrict__ pb2,
        float* __restrict__ pout) {
    __shared__ ushort Asl[2][128 * 64];
    __shared__ ushort Bsl[2][64 * 64];
    int bx = blockIdx.x;
    const ushort *Am, *Af, *W1, *W2; const float *b1, *b2; float* out;
    if (bx < NN / 128) {
        Am = imsgB; Af = instB; W1 = iw1T; W2 = iw2T; b1 = ib1; b2 = ib2; out = iout;
    } else {
        bx -= NN / 128;
        Am = pmsgB; Af = phraB; W1 = pw1T; W2 = pw2T; b1 = pb1; b2 = pb2; out = pout;
    }
    int bm = bx * 128, bn = blockIdx.y * 64;
    int t = threadIdx.x;
    const int lane = t & 63, w = t >> 6;
    const int wr = (w >> 1) * 64, wc = (w & 1) * 32;
    const int lr = lane & 15, lk = lane >> 4;
    f32x4 acc1[4][2] = {};
    f32x4 acc2[4][2] = {};

    int cur = 0;
    stage_tiles<64>(Am, W1, bm, bn, 0, Asl[0], Bsl[0], t);
    auto run = [&](const ushort* A, const ushort* B, f32x4 (&acc)[4][2],
                   const ushort* An, const ushort* Bn) {
        for (int k0 = 0; k0 < DD; k0 += 64) {
            int nxt = cur ^ 1;
            if (k0 + 64 < DD) {
                stage_tiles<64>(A, B, bm, bn, k0 + 64, Asl[nxt], Bsl[nxt], t);
                ASM_VMCNT(6);
            } else if (An) {
                stage_tiles<64>(An, Bn, bm, bn, 0, Asl[nxt], Bsl[nxt], t);
                ASM_VMCNT(6);
            } else {
                ASM_VMCNT(0);
            }
            BARRIER();
            compute_tiles<2>(Asl[cur], Bsl[cur], acc, wr, wc, lr, lk);
            BARRIER();
            cur = nxt;
        }
    };
    run(Am, W1, acc1, Af, W2);
    run(Af, W2, acc2, nullptr, nullptr);

    #pragma unroll
    for (int m = 0; m < 4; m++) {
        int row = bm + wr + m * 16 + lk * 4;
        #pragma unroll
        for (int n = 0; n < 2; n++) {
            int col = bn + wc + n * 16 + lr;
            float vb1 = b1[col], vb2 = b2[col];
            #pragma unroll
            for (int r = 0; r < 4; r++) {
                float v = b2f(Am[(size_t)(row + r) * DD + col])
                        + fmaxf(acc1[m][n][r] + vb1, 0.f)
                        + fmaxf(acc2[m][n][r] + vb2, 0.f);
                out[(size_t)(row + r) * DD + col] = v;
            }
        }
    }
}

// ---------------------------------------------------------------------------
// Counting sort: histogram + scan (scatter is folded into gate_kernel).
__global__ void hist_kernel(const int* __restrict__ s_idx, const int* __restrict__ o_idx,
                            const int* __restrict__ c_idx,
                            int* cntS, int* cntO, int* cntC) {
    int e = blockIdx.x * blockDim.x + threadIdx.x;
    if (e >= EE) return;
    atomicAdd(&cntS[s_idx[e]], 1);
    atomicAdd(&cntO[o_idx[e]], 1);
    atomicAdd(&cntC[c_idx[e]], 1);
}

__global__ __launch_bounds__(1024) void scan3_kernel(
        const int* __restrict__ cntS, const int* __restrict__ cntO,
        const int* __restrict__ cntC,
        int* __restrict__ startS, int* __restrict__ startO, int* __restrict__ startC) {
    const int* cnt; int* start; int n;
    if (blockIdx.x == 0)      { cnt = cntS; start = startS; n = NN; }
    else if (blockIdx.x == 1) { cnt = cntO; start = startO; n = NN; }
    else                      { cnt = cntC; start = startC; n = PP; }
    __shared__ int sh[1024];
    int t = threadIdx.x;
    int per = n >> 10;
    int base = t * per;
    int s = 0;
    for (int i = 0; i < per; i++) s += cnt[base + i];
    sh[t] = s;
    __syncthreads();
    for (int off = 1; off < 1024; off <<= 1) {
        int v = (t >= off) ? sh[t - off] : 0;
        __syncthreads();
        sh[t] += v;
        __syncthreads();
    }
    int ex = (t == 0) ? 0 : sh[t - 1];
    for (int i = 0; i < per; i++) { start[base + i] = ex; ex += cnt[base + i]; }
    if (t == 1023) start[n] = ex;
}

// ---------------------------------------------------------------------------
// Per-edge gates; computes CSR slot (scatter fused) and writes packed entries.
__global__ __launch_bounds__(256) void gate_kernel(
        const int* __restrict__ s_idx, const int* __restrict__ o_idx,
        const int* __restrict__ c_idx,
        const int* __restrict__ startS, const int* __restrict__ startO,
        const int* __restrict__ startC,
        int* __restrict__ curS, int* __restrict__ curO, int* __restrict__ curC,
        const ushort* __restrict__ Ti, const ushort* __restrict__ Tp,
        int2* __restrict__ pkS, int2* __restrict__ pkO, int4* __restrict__ pkC) {
    int gid = blockIdx.x * 256 + threadIdx.x;
    int e = gid >> 6, lane = gid & 63;
    if (e >= EE) return;
    int s = s_idx[e], o = o_idx[e], c = c_idx[e];
    const unsigned int* tpc = (const unsigned int*)(Tp + (size_t)c * G4);
    const unsigned int* tis = (const unsigned int*)(Ti + (size_t)s * G4);
    const unsigned int* tio = (const unsigned int*)(Ti + (size_t)o * G4);
    auto pairSig = [](unsigned int a, unsigned int b) {
        float lo = __uint_as_float(a << 16) + __uint_as_float(b << 16);
        float hi = __uint_as_float(a & 0xffff0000u) + __uint_as_float(b & 0xffff0000u);
        return sigmoid_relu(lo) + sigmoid_relu(hi);
    };
    float s0 = pairSig(tpc[lane],       tis[lane]);
    float s1 = pairSig(tpc[64 + lane],  tio[64 + lane]);
    float s2 = pairSig(tpc[128 + lane], tio[128 + lane]);
    float s3 = pairSig(tpc[192 + lane], tis[192 + lane]);
    #pragma unroll
    for (int off = 32; off; off >>= 1) {
        s0 += __shfl_xor(s0, off);
        s1 += __shfl_xor(s1, off);
        s2 += __shfl_xor(s2, off);
        s3 += __shfl_xor(s3, off);
    }
    if (lane == 0) {
        const float inv = 1.0f / 128.0f;
        int ps = startS[s] + atomicAdd(&curS[s], 1);
        int po = startO[o] + atomicAdd(&curO[o], 1);
        int pc = startC[c] + atomicAdd(&curC[c], 1);
        pkS[ps] = make_int2(c, __float_as_int(s0 * inv));
        pkO[po] = make_int2(c, __float_as_int(s1 * inv));
        pkC[pc] = make_int4(o, s, __float_as_int(s2 * inv), __float_as_int(s3 * inv));
    }
}

// ---------------------------------------------------------------------------
// Segment means, D-quartered + XCD-pinned (R8: FETCH 106->17.5 MB) with
// shfl-broadcast pk (R9: no vmcnt drain).  R10: 2 edges per wave-step —
// lanes 0..31 process edge j, lanes 32..63 edge j+1; each lane loads uint4
// (8 dims, 32 lanes = full quarter).  Halves iterations, doubles bytes per
// load; partial sums combined via one shfl_xor(32) pass.
__device__ __forceinline__ void acc8(float* a, uint4 v, float g) {
    a[0] += g * lo16(v.x); a[1] += g * hi16(v.x);
    a[2] += g * lo16(v.y); a[3] += g * hi16(v.y);
    a[4] += g * lo16(v.z); a[5] += g * hi16(v.z);
    a[6] += g * lo16(v.w); a[7] += g * hi16(v.w);
}

__global__ __launch_bounds__(256) void seg_kernel(
        const ushort* __restrict__ phraB, const ushort* __restrict__ instB,
        const int2* __restrict__ pkS, const int* __restrict__ startS,
        const int2* __restrict__ pkO, const int* __restrict__ startO,
        const int4* __restrict__ pkC, const int* __restrict__ startC,
        ushort* __restrict__ imsgB, ushort* __restrict__ pmsgB) {
    __shared__ float lds[4][32 * 9];
    int bid = blockIdx.x;
    int x = bid & 7;
    int q = x >> 1;
    int sub = ((bid >> 3) << 1) + (x & 1);
    int qoff = q * 256;
    int w = threadIdx.x >> 6, lane = threadIdx.x & 63;
    int half = lane >> 5, l32 = lane & 31;
    float a[8];
    #pragma unroll
    for (int k = 0; k < 8; k++) a[k] = 0.f;
    bool instSide = sub < NN / 2;
    int lenScale;
    ushort* msgB;
    int base2;
    if (instSide) {
        int node = sub * 2 + (w >> 1);
        const int2* pk_list = (w & 1) ? pkO : pkS;
        const int*  start   = (w & 1) ? startO : startS;
        int b = start[node], e = start[node + 1];
        lenScale = e - b;
        for (int base = b; base < e; base += 64) {
            int n = min(64, e - base);
            int2 pkv = pk_list[base + min(lane, n - 1)];   // one coalesced load
            int   c0 = __shfl(pkv.x, 0);
            int   c1 = __shfl(pkv.x, 1 < n ? 1 : 0);
            float g0 = __int_as_float(__shfl(pkv.y, 0));
            float g1 = (1 < n) ? __int_as_float(__shfl(pkv.y, 1)) : 0.f;
            int   myc = half ? c1 : c0;
            float myg = half ? g1 : g0;
            uint4 v = *(const uint4*)(phraB + (size_t)myc * DD + qoff + l32 * 8);
            for (int j = 2; j < n; j += 2) {
                int   d0 = __shfl(pkv.x, j);
                int   d1 = __shfl(pkv.x, j + 1 < n ? j + 1 : j);
                float h0 = __int_as_float(__shfl(pkv.y, j));
                float h1 = (j + 1 < n) ? __int_as_float(__shfl(pkv.y, j + 1)) : 0.f;
                int   nc = half ? d1 : d0;
                float ng = half ? h1 : h0;
                uint4 vn = *(const uint4*)(phraB + (size_t)nc * DD + qoff + l32 * 8);
                acc8(a, v, myg);
                v = vn; myg = ng;
            }
            acc8(a, v, myg);
        }
        msgB = imsgB; base2 = sub * 2;
    } else {
        int pbx = sub - NN / 2;
        int p = pbx * 2 + (w >> 1);
        int cb = startC[p], ce = startC[p + 1];
        lenScale = ce - cb;
        int mid = cb + ((ce - cb) >> 1);
        int mb = (w & 1) ? mid : cb;       // contiguous halves (coalesced chunks)
        int me = (w & 1) ? ce : mid;
        for (int base = mb; base < me; base += 64) {
            int n = min(64, me - base);
            int4 pkv = pkC[base + min(lane, n - 1)];
            int   o0  = __shfl(pkv.x, 0);
            int   o1  = __shfl(pkv.x, 1 < n ? 1 : 0);
            int   si0 = __shfl(pkv.y, 0);
            int   si1 = __shfl(pkv.y, 1 < n ? 1 : 0);
            float go0 = __int_as_float(__shfl(pkv.z, 0));
            float go1 = (1 < n) ? __int_as_float(__shfl(pkv.z, 1)) : 0.f;
            float gs0 = __int_as_float(__shfl(pkv.w, 0));
            float gs1 = (1 < n) ? __int_as_float(__shfl(pkv.w, 1)) : 0.f;
            int   myo = half ? o1 : o0,  mys = half ? si1 : si0;
            float mygo = half ? go1 : go0, mygs = half ? gs1 : gs0;
            uint4 vo = *(const uint4*)(instB + (size_t)myo * DD + qoff + l32 * 8);
            uint4 vs = *(const uint4*)(instB + (size_t)mys * DD + qoff + l32 * 8);
            for (int j = 2; j < n; j += 2) {
                int   no0  = __shfl(pkv.x, j);
                int   no1  = __shfl(pkv.x, j + 1 < n ? j + 1 : j);
                int   ns0  = __shfl(pkv.y, j);
                int   ns1  = __shfl(pkv.y, j + 1 < n ? j + 1 : j);
                float ngo0 = __int_as_float(__shfl(pkv.z, j));
                float ngo1 = (j + 1 < n) ? __int_as_float(__shfl(pkv.z, j + 1)) : 0.f;
                float ngs0 = __int_as_float(__shfl(pkv.w, j));
                float ngs1 = (j + 1 < n) ? __int_as_float(__shfl(pkv.w, j + 1)) : 0.f;
                int   nno = half ? no1 : no0,  nns = half ? ns1 : ns0;
                float ngo = half ? ngo1 : ngo0, ngs = half ? ngs1 : ngs0;
                uint4 vno = *(const uint4*)(instB + (size_t)nno * DD + qoff + l32 * 8);
                uint4 vns = *(const uint4*)(instB + (size_t)nns * DD + qoff + l32 * 8);
                acc8(a, vo, mygo);
                acc8(a, vs, mygs);
                vo = vno; vs = vns; mygo = ngo; mygs = ngs;
            }
            acc8(a, vo, mygo);
            acc8(a, vs, mygs);
        }
        msgB = pmsgB; base2 = pbx * 2;
    }
    // combine lane halves (edge j + edge j+1 partial sums share dims)
    #pragma unroll
    for (int k = 0; k < 8; k++) a[k] += __shfl_xor(a[k], 32);
    float scale = 0.5f / (float)max(lenScale, 1);
    if (half == 0) {
        #pragma unroll
        for (int k = 0; k < 8; k++) lds[w][l32 * 9 + k] = a[k] * scale;
    }
    __syncthreads();
    if (threadIdx.x < 64) {
        int nodeSel = threadIdx.x >> 5;   // which of the block's 2 rows
        int l = threadIdx.x & 31;
        int w0 = nodeSel * 2;
        float s0 = lds[w0][l * 9 + 0] + lds[w0 + 1][l * 9 + 0];
        float s1 = lds[w0][l * 9 + 1] + lds[w0 + 1][l * 9 + 1];
        float s2 = lds[w0][l * 9 + 2] + lds[w0 + 1][l * 9 + 2];
        float s3 = lds[w0][l * 9 + 3] + lds[w0 + 1][l * 9 + 3];
        float s4 = lds[w0][l * 9 + 4] + lds[w0 + 1][l * 9 + 4];
        float s5 = lds[w0][l * 9 + 5] + lds[w0 + 1][l * 9 + 5];
        float s6 = lds[w0][l * 9 + 6] + lds[w0 + 1][l * 9 + 6];
        float s7 = lds[w0][l * 9 + 7] + lds[w0 + 1][l * 9 + 7];
        uint4 o;
        o.x = pack2(s0, s1);
        o.y = pack2(s2, s3);
        o.z = pack2(s4, s5);
        o.w = pack2(s6, s7);
        *(uint4*)&msgB[(size_t)(base2 + nodeSel) * DD + qoff + l * 8] = o;
    }
}

// ---------------------------------------------------------------------------
extern "C" void kernel_launch(void* const* d_in, const int* in_sizes, int n_in,
                              void* d_out, int out_size, void* d_ws, size_t ws_size,
                              hipStream_t stream) {
    (void)in_sizes; (void)n_in; (void)out_size; (void)ws_size;
    const float* inst_feat = (const float*)d_in[0];
    const float* phra_feat = (const float*)d_in[1];
    const int*   conn      = (const int*)d_in[2];
    const int*   clu       = (const int*)d_in[3];
    const float* psW = (const float*)d_in[4];  const float* psB = (const float*)d_in[5];
    const float* poW = (const float*)d_in[6];  const float* poB = (const float*)d_in[7];
    const float* opW = (const float*)d_in[8];  const float* opB = (const float*)d_in[9];
    const float* spW = (const float*)d_in[10]; const float* spB = (const float*)d_in[11];
    const float* iw1W = (const float*)d_in[12]; const float* iw1B = (const float*)d_in[13];
    const float* iw2W = (const float*)d_in[14]; const float* iw2B = (const float*)d_in[15];
    const float* pw1W = (const float*)d_in[16]; const float* pw1B = (const float*)d_in[17];
    const float* pw2W = (const float*)d_in[18]; const float* pw2B = (const float*)d_in[19];
    const int* s_idx = conn;
    const int* o_idx = conn + EE;

    char* ws = (char*)d_ws;
    size_t off = 0;
    auto alloc = [&](size_t bytes) {
        char* p = ws + off;
        off += (bytes + 255) & ~(size_t)255;
        return p;
    };
    ushort* instB = (ushort*)alloc((size_t)NN * DD * 2);
    ushort* phraB = (ushort*)alloc((size_t)PP * DD * 2);
    ushort* WiT   = (ushort*)alloc((size_t)G4 * DD * 2);
    ushort* WpT   = (ushort*)alloc((size_t)G4 * DD * 2);
    ushort* iw1T  = (ushort*)alloc((size_t)DD * DD * 2);
    ushort* iw2T  = (ushort*)alloc((size_t)DD * DD * 2);
    ushort* pw1T  = (ushort*)alloc((size_t)DD * DD * 2);
    ushort* pw2T  = (ushort*)alloc((size_t)DD * DD * 2);
    float* biascat = (float*)alloc(G4 * 4);
    ushort* TiB   = (ushort*)alloc((size_t)NN * G4 * 2);
    ushort* TpB   = (ushort*)alloc((size_t)PP * G4 * 2);
    int* cntBlock = (int*)alloc((size_t)NCNT * 4);
    int* cntS = cntBlock;      int* cntO = cntS + NN;  int* cntC = cntO + NN;
    int* curS = cntC + PP;     int* curO = curS + NN;  int* curC = curO + NN;
    int* startS = (int*)alloc((NN + 1) * 4);
    int* startO = (int*)alloc((NN + 1) * 4);
    int* startC = (int*)alloc((PP + 1) * 4);
    int2* pkS   = (int2*)alloc((size_t)EE * 8);
    int2* pkO   = (int2*)alloc((size_t)EE * 8);
    int4* pkC   = (int4*)alloc((size_t)EE * 16);
    ushort* imsgB = (ushort*)alloc((size_t)NN * DD * 2);
    ushort* pmsgB = (ushort*)alloc((size_t)PP * DD * 2);

    float* inst_out = (float*)d_out;
    float* phra_out = inst_out + (size_t)NN * DD;

    // Fused prep: counter zeroing + bf16 casts + weight pack/transpose
    prep_kernel<<<NB_ZERO + NB_F2B + NB_PACK + NB_WT, 256, 0, stream>>>(
        cntBlock, inst_feat, phra_feat, instB, phraB,
        psW, poW, opW, spW, psB, poB, opB, spB, WiT, WpT, biascat,
        iw1W, iw2W, pw1W, pw2W, iw1T, iw2T, pw1T, pw2T);

    // CSR build (scatter folded into gate_kernel)
    hist_kernel<<<EE / 256, 256, 0, stream>>>(s_idx, o_idx, clu, cntS, cntO, cntC);
    scan3_kernel<<<3, 1024, 0, stream>>>(cntS, cntO, cntC, startS, startO, startC);

    // Gate tables (bf16 MFMA, bias folded into Tp)
    mfma_tables_kernel<<<dim3((NN + PP) / 128, G4 / 64), 256, 0, stream>>>(
        instB, WiT, phraB, WpT, biascat, TiB, TpB);

    // Gates -> packed CSR entries (scatter fused)
    gate_kernel<<<(EE * 64) / 256, 256, 0, stream>>>(
        s_idx, o_idx, clu, startS, startO, startC, curS, curO, curC,
        TiB, TpB, pkS, pkO, pkC);

    // Segment means (quartered, XCD-pinned, 2-edge-per-step uint4 pipeline)
    seg_kernel<<<(NN / 2 + PP / 2) * 4, 256, 0, stream>>>(
        phraB, instB, pkS, startS, pkO, startO, pkC, startC, imsgB, pmsgB);

    // Fused refine (128x64 tiles, 768 blocks, counted-vmcnt pipeline)
    mfma_refine_kernel<<<dim3((NN + PP) / 128, DD / 64), 256, 0, stream>>>(
        imsgB, instB, iw1T, iw2T, iw1B, iw2B, inst_out,
        pmsgB, phraB, pw1T, pw2T, pw1B, pw2B, phra_out);
}